// Round 7
// baseline (709.256 us; speedup 1.0000x reference)
//
#include <hip/hip_runtime.h>
#include <hip/hip_bf16.h>

#define CDIM 384
#define NQKV 1152
#define HEADS 12
#define SHIFT_ 4
#define SCALE_Q 0.17677669529663687f  // 32^-0.5

typedef __attribute__((ext_vector_type(8))) short bf16x8;
typedef __attribute__((ext_vector_type(4))) float f32x4;
typedef __attribute__((ext_vector_type(4))) float float4_t;
typedef __attribute__((ext_vector_type(4))) unsigned u32x4;

__device__ inline short f2bf(float f) {
    union { float f; unsigned u; } v; v.f = f;
    unsigned r = v.u + 0x7FFFu + ((v.u >> 16) & 1u);
    return (short)(r >> 16);
}

__device__ inline unsigned cvtpk(float lo, float hi) {
    unsigned r;
    asm volatile("v_cvt_pk_bf16_f32 %0, %1, %2" : "=v"(r) : "v"(lo), "v"(hi));
    return r;
}

__device__ inline bf16x8 mk8(unsigned w0, unsigned w1, unsigned w2, unsigned w3) {
    u32x4 t = {w0, w1, w2, w3};
    return __builtin_bit_cast(bf16x8, t);
}

// Regroup: two acc tiles (rows 0-15 from pairs p0,p1; rows 16-31 from p2,p3;
// per-lane col=lane&15, rows lhi*4+r packed as bf16 pairs) -> MFMA operand
// fragment (per-lane col=lane&15, rows lhi*8..lhi*8+7).
__device__ inline bf16x8 regroup(unsigned p0, unsigned p1, unsigned p2,
                                 unsigned p3, int lane) {
    int lhi = (lane >> 4) & 3;
    int s0 = (lane & 15) + ((lhi & 1) ? 32 : 0);
    int s1 = s0 + 16;
    unsigned a0 = __shfl(p0, s0), b0 = __shfl(p2, s0);
    unsigned a1 = __shfl(p1, s0), b1 = __shfl(p3, s0);
    unsigned a2 = __shfl(p0, s1), b2 = __shfl(p2, s1);
    unsigned a3 = __shfl(p1, s1), b3 = __shfl(p3, s1);
    bool hi = lhi >= 2;
    return mk8(hi ? b0 : a0, hi ? b1 : a1, hi ? b2 : a2, hi ? b3 : a3);
}

__device__ inline void gl16(const short* g, const short* l) {
    __builtin_amdgcn_global_load_lds((const __attribute__((address_space(1))) void*)g,
                                     (__attribute__((address_space(3))) void*)l, 16, 0, 0);
}

__device__ inline int invswz(int c) {
    int b2 = (c >> 2) & 1, b3 = (c >> 3) & 1, b4 = (c >> 4) & 1;
    return (c & ~7) | ((b2 ^ b4) << 2) | (((((c >> 1) & 1)) ^ b3) << 1) | ((c & 1) ^ b2 ^ b4);
}

// ---------------- prep: weight transpose->bf16, bias matrix (transposed) ---
__global__ void prep_kernel(const float* __restrict__ qkv_w,
                            const float* __restrict__ proj_w,
                            const float* __restrict__ bias_table,
                            const int* __restrict__ rel_index,
                            short* __restrict__ qkvwt,
                            short* __restrict__ projwt,
                            float* __restrict__ biasT) {
    int t = blockIdx.x * 256 + threadIdx.x;
    if (t < NQKV * CDIM) {             // qkvwt[n][k] = qkv_w[k][n]
        int n = t / CDIM, k = t - n * CDIM;
        qkvwt[t] = f2bf(qkv_w[k * NQKV + n]);
    }
    if (t < CDIM * CDIM) {             // projwt[n][k] = proj_w[k][n]
        int n = t / CDIM, k = t - n * CDIM;
        projwt[t] = f2bf(proj_w[k * CDIM + n]);
    }
    if (t < HEADS * 64 * 64) {         // biasT[h][key j][query i]
        int h = t >> 12, jq = t & 4095;
        int j = jq >> 6, i = jq & 63;
        biasT[t] = bias_table[rel_index[i * 64 + j] * HEADS + h];
    }
}

// ---------------- fused qkv + attention: one block per window --------------
// 4 waves, wave = 3 heads. Xs staged once (48K); Q/K/V/S/P entirely in
// registers (W-as-A + X-as-A MFMA layouts + shfl regroup). LDS = Xs + regbuf
// = 49408 B -> 3 blocks/CU (3 waves/SIMD).
__global__ __launch_bounds__(256, 3) void fused_qa(
    const float* __restrict__ x, const short* __restrict__ qkvwt,
    const float* __restrict__ qkv_b, const float* __restrict__ biasT,
    short* __restrict__ attno)
{
    __shared__ __attribute__((aligned(16))) char smem[49408];
    char* xs = smem;                           // [64][384] bf16, XOR-swizzled
    int tid = threadIdx.x;
    int lane = tid & 63, wv = tid >> 6;
    int lrow = lane & 15, lhi = lane >> 4;
    int* regbuf = (int*)(smem + 49152);

    int hw = blockIdx.x;
    int w = (hw & 7) * 256 + (hw >> 3);        // XCD-chunked window id
    int b = w >> 6, wIdx = w & 63;
    bool needmask = ((wIdx >> 3) == 7) || ((wIdx & 7) == 7);

    if (tid < 64) {                            // shift-mask region ids
        int gh = ((wIdx >> 3) << 3) + (tid >> 3);
        int gw = (wIdx & 7) * 8 + (tid & 7);
        int rh = gh < 56 ? 0 : (gh < 60 ? 1 : 2);
        int rw = gw < 56 ? 0 : (gw < 60 ? 1 : 2);
        regbuf[tid] = rh * 3 + rw;
    }

    // ---- stage x window -> Xs (bf16, XOR-swizzled), once ----
    #pragma unroll
    for (int it = 0; it < 6; it++) {
        int c = it * 256 + tid;                // 1536 chunks of 16 floats
        int tok = c / 24, kc = (c - tok * 24) * 16;
        int gh = ((wIdx >> 3) << 3) + (tok >> 3);
        int gw = (wIdx & 7) * 8 + (tok & 7);
        int sh_ = (gh + SHIFT_) & 63, sw_ = (gw + SHIFT_) & 63;
        const float* src = x + (size_t)(b * 4096 + sh_ * 64 + sw_) * CDIM + kc;
        float4_t a0 = *(const float4_t*)(src);
        float4_t a1 = *(const float4_t*)(src + 4);
        float4_t a2 = *(const float4_t*)(src + 8);
        float4_t a3 = *(const float4_t*)(src + 12);
        bf16x8 w0, w1;
        #pragma unroll
        for (int i = 0; i < 4; i++) {
            w0[i] = f2bf(a0[i]); w0[4 + i] = f2bf(a1[i]);
            w1[i] = f2bf(a2[i]); w1[4 + i] = f2bf(a3[i]);
        }
        int base = tok * 768 + kc * 2, sw = (tok & 7) << 4;
        *(bf16x8*)(xs + (base ^ sw)) = w0;
        *(bf16x8*)(xs + ((base + 16) ^ sw)) = w1;
    }
    __syncthreads();                           // only block-wide barrier

    int aswz = (lrow & 7) << 4;
    f32x4 zero = {0.f, 0.f, 0.f, 0.f};

    int rq[4], rk[4][4];                       // region ids (query/key view)
    #pragma unroll
    for (int qt = 0; qt < 4; qt++) rq[qt] = regbuf[qt * 16 + lrow];
    #pragma unroll
    for (int kt = 0; kt < 4; kt++)
        #pragma unroll
        for (int r = 0; r < 4; r++) rk[kt][r] = regbuf[kt * 16 + lhi * 4 + r];

    for (int hi = 0; hi < 3; hi++) {
        int h = wv * 3 + hi;
        // ---- qkv GEMM: Q,K via W-as-A (acc col=token); V via X-as-A ----
        const short* wq0 = qkvwt + (size_t)(h * 32 + lrow) * CDIM + lhi * 8;
        const short* wq1 = wq0 + 16 * CDIM;
        const short* wk0 = qkvwt + (size_t)(CDIM + h * 32 + lrow) * CDIM + lhi * 8;
        const short* wk1 = wk0 + 16 * CDIM;
        const short* wv0 = qkvwt + (size_t)(2 * CDIM + h * 32 + lrow) * CDIM + lhi * 8;
        const short* wv1 = wv0 + 16 * CDIM;
        f32x4 aq[2][4], ak[2][4], av[4][2];
        #pragma unroll
        for (int i = 0; i < 4; i++) {
            aq[0][i] = zero; aq[1][i] = zero; ak[0][i] = zero; ak[1][i] = zero;
            av[i][0] = zero; av[i][1] = zero;
        }
        #pragma unroll
        for (int ks = 0; ks < 12; ks++) {
            bf16x8 fq0 = *(const bf16x8*)(wq0 + ks * 32);
            bf16x8 fq1 = *(const bf16x8*)(wq1 + ks * 32);
            bf16x8 fk0 = *(const bf16x8*)(wk0 + ks * 32);
            bf16x8 fk1 = *(const bf16x8*)(wk1 + ks * 32);
            bf16x8 fv0 = *(const bf16x8*)(wv0 + ks * 32);
            bf16x8 fv1 = *(const bf16x8*)(wv1 + ks * 32);
            bf16x8 xf[4];
            #pragma unroll
            for (int tt = 0; tt < 4; tt++)
                xf[tt] = *(const bf16x8*)(xs + (((tt * 16 + lrow) * 768 + ks * 64 + lhi * 16) ^ aswz));
            __builtin_amdgcn_s_setprio(1);
            #pragma unroll
            for (int tt = 0; tt < 4; tt++) {
                aq[0][tt] = __builtin_amdgcn_mfma_f32_16x16x32_bf16(fq0, xf[tt], aq[0][tt], 0, 0, 0);
                aq[1][tt] = __builtin_amdgcn_mfma_f32_16x16x32_bf16(fq1, xf[tt], aq[1][tt], 0, 0, 0);
                ak[0][tt] = __builtin_amdgcn_mfma_f32_16x16x32_bf16(fk0, xf[tt], ak[0][tt], 0, 0, 0);
                ak[1][tt] = __builtin_amdgcn_mfma_f32_16x16x32_bf16(fk1, xf[tt], ak[1][tt], 0, 0, 0);
                av[tt][0] = __builtin_amdgcn_mfma_f32_16x16x32_bf16(xf[tt], fv0, av[tt][0], 0, 0, 0);
                av[tt][1] = __builtin_amdgcn_mfma_f32_16x16x32_bf16(xf[tt], fv1, av[tt][1], 0, 0, 0);
            }
            __builtin_amdgcn_s_setprio(0);
        }
        // ---- V epilogue -> in-register B fragments (frees av) ----
        // av[tt][dt]: col(lane&15)=dim dt*16+lrow', rows=tokens tt*16+lhi*4+r.
        // vfrag[ks2][dt]: B-op col=dim, rows lhi*8+e = keys ks2*32..+31
        // built from tiles av[2ks2][dt] (keys 0-15) + av[2ks2+1][dt] (16-31).
        float bv0 = qkv_b[2 * CDIM + h * 32 + lrow];
        float bv1 = qkv_b[2 * CDIM + h * 32 + 16 + lrow];
        bf16x8 vfrag[2][2];
        #pragma unroll
        for (int ks2 = 0; ks2 < 2; ks2++) {
            #pragma unroll
            for (int dt = 0; dt < 2; dt++) {
                float bv = dt ? bv1 : bv0;
                unsigned p0 = cvtpk(av[2 * ks2][dt][0] + bv, av[2 * ks2][dt][1] + bv);
                unsigned p1 = cvtpk(av[2 * ks2][dt][2] + bv, av[2 * ks2][dt][3] + bv);
                unsigned p2 = cvtpk(av[2 * ks2 + 1][dt][0] + bv, av[2 * ks2 + 1][dt][1] + bv);
                unsigned p3 = cvtpk(av[2 * ks2 + 1][dt][2] + bv, av[2 * ks2 + 1][dt][3] + bv);
                vfrag[ks2][dt] = regroup(p0, p1, p2, p3, lane);
            }
        }
        // ---- Q/K epilogue -> fragments (bias, scale, pack, regroup) ----
        float bq[2][4], bk[2][4];
        #pragma unroll
        for (int dt = 0; dt < 2; dt++)
            #pragma unroll
            for (int r = 0; r < 4; r++) {
                bq[dt][r] = qkv_b[h * 32 + dt * 16 + lhi * 4 + r];
                bk[dt][r] = qkv_b[CDIM + h * 32 + dt * 16 + lhi * 4 + r];
            }
        bf16x8 qf[4], kf[4];
        #pragma unroll
        for (int tt = 0; tt < 4; tt++) {
            unsigned p0 = cvtpk((aq[0][tt][0] + bq[0][0]) * SCALE_Q, (aq[0][tt][1] + bq[0][1]) * SCALE_Q);
            unsigned p1 = cvtpk((aq[0][tt][2] + bq[0][2]) * SCALE_Q, (aq[0][tt][3] + bq[0][3]) * SCALE_Q);
            unsigned p2 = cvtpk((aq[1][tt][0] + bq[1][0]) * SCALE_Q, (aq[1][tt][1] + bq[1][1]) * SCALE_Q);
            unsigned p3 = cvtpk((aq[1][tt][2] + bq[1][2]) * SCALE_Q, (aq[1][tt][3] + bq[1][3]) * SCALE_Q);
            qf[tt] = regroup(p0, p1, p2, p3, lane);
            p0 = cvtpk(ak[0][tt][0] + bk[0][0], ak[0][tt][1] + bk[0][1]);
            p1 = cvtpk(ak[0][tt][2] + bk[0][2], ak[0][tt][3] + bk[0][3]);
            p2 = cvtpk(ak[1][tt][0] + bk[1][0], ak[1][tt][1] + bk[1][1]);
            p3 = cvtpk(ak[1][tt][2] + bk[1][2], ak[1][tt][3] + bk[1][3]);
            kf[tt] = regroup(p0, p1, p2, p3, lane);
        }
        // ---- S^T = K Q^T : rows=keys(lhi*4+r), cols=queries(lane&15) ----
        f32x4 st[4][4];
        __builtin_amdgcn_s_setprio(1);
        #pragma unroll
        for (int kt = 0; kt < 4; kt++)
            #pragma unroll
            for (int qt = 0; qt < 4; qt++)
                st[kt][qt] = __builtin_amdgcn_mfma_f32_16x16x32_bf16(kf[kt], qf[qt], zero, 0, 0, 0);
        __builtin_amdgcn_s_setprio(0);
        // ---- softmax per query (lane-local row) + P fragments ----
        const float* bT = biasT + h * 4096 + lrow;  // + key*64 + qt*16
        bf16x8 pa[4][2];
        #pragma unroll
        for (int qt = 0; qt < 4; qt++) {
            float pv[16]; float sum = 0.f;
            #pragma unroll
            for (int kt = 0; kt < 4; kt++)
                #pragma unroll
                for (int r = 0; r < 4; r++) {
                    float v = st[kt][qt][r] + bT[(kt * 16 + lhi * 4 + r) * 64 + qt * 16];
                    float p = __expf(v);
                    p = (needmask && (rq[qt] != rk[kt][r])) ? 0.f : p;
                    pv[kt * 4 + r] = p; sum += p;
                }
            sum += __shfl_xor(sum, 16);
            sum += __shfl_xor(sum, 32);
            float rcp = 1.0f / sum;
            unsigned a0 = cvtpk(pv[0] * rcp, pv[1] * rcp);
            unsigned a1 = cvtpk(pv[2] * rcp, pv[3] * rcp);
            unsigned a2 = cvtpk(pv[4] * rcp, pv[5] * rcp);
            unsigned a3 = cvtpk(pv[6] * rcp, pv[7] * rcp);
            pa[qt][0] = regroup(a0, a1, a2, a3, lane);
            a0 = cvtpk(pv[8] * rcp,  pv[9] * rcp);
            a1 = cvtpk(pv[10] * rcp, pv[11] * rcp);
            a2 = cvtpk(pv[12] * rcp, pv[13] * rcp);
            a3 = cvtpk(pv[14] * rcp, pv[15] * rcp);
            pa[qt][1] = regroup(a0, a1, a2, a3, lane);
        }
        // ---- PV: out[query][dim], V entirely in registers ----
        f32x4 ao[4][2];
        #pragma unroll
        for (int qt = 0; qt < 4; qt++) { ao[qt][0] = zero; ao[qt][1] = zero; }
        __builtin_amdgcn_s_setprio(1);
        #pragma unroll
        for (int ks2 = 0; ks2 < 2; ks2++)
            #pragma unroll
            for (int qt = 0; qt < 4; qt++) {
                ao[qt][0] = __builtin_amdgcn_mfma_f32_16x16x32_bf16(pa[qt][ks2], vfrag[ks2][0], ao[qt][0], 0, 0, 0);
                ao[qt][1] = __builtin_amdgcn_mfma_f32_16x16x32_bf16(pa[qt][ks2], vfrag[ks2][1], ao[qt][1], 0, 0, 0);
            }
        __builtin_amdgcn_s_setprio(0);
        // ---- direct bf16 stores (16-lane groups write 32B segments) ----
        short* abase = attno + (size_t)(w * 64) * CDIM + h * 32;
        #pragma unroll
        for (int qt = 0; qt < 4; qt++)
            #pragma unroll
            for (int dt = 0; dt < 2; dt++)
                #pragma unroll
                for (int r = 0; r < 4; r++) {
                    int token = qt * 16 + lhi * 4 + r;
                    abase[(size_t)token * CDIM + dt * 16 + lrow] = f2bf(ao[qt][dt][r]);
                }
    }
}

// ---------------- GEMM2: out = attno @ proj_w^T + b, window-reverse --------
__global__ __launch_bounds__(256) void gemm_proj(
    const short* __restrict__ a, const short* __restrict__ wt,
    const float* __restrict__ proj_b, float* __restrict__ out)
{
    __shared__ alignas(16) short As[4096];
    __shared__ alignas(16) short Bs[4096];
    int tid = threadIdx.x;
    int hw = blockIdx.x;                       // 3072 blocks, %8==0
    int lb = (hw & 7) * 384 + (hw >> 3);
    int bm = lb / 3, bn = lb - bm * 3;
    int m0 = bm * 128, n0 = bn * 128;

    int lane = tid & 63, wv = tid >> 6;
    int c0 = wv * 128 + lane, c1 = c0 + 64;
    int l0 = invswz(c0), l1 = invswz(c1);
    const short* Ag0 = a + (size_t)(m0 + (l0 >> 2)) * CDIM + (l0 & 3) * 8;
    const short* Ag1 = a + (size_t)(m0 + (l1 >> 2)) * CDIM + (l1 & 3) * 8;
    const short* Bg0 = wt + (size_t)(n0 + (l0 >> 2)) * CDIM + (l0 & 3) * 8;
    const short* Bg1 = wt + (size_t)(n0 + (l1 >> 2)) * CDIM + (l1 & 3) * 8;
    const short* Adst0 = (const short*)((const char*)As + wv * 2048);
    const short* Adst1 = (const short*)((const char*)As + wv * 2048 + 1024);
    const short* Bdst0 = (const short*)((const char*)Bs + wv * 2048);
    const short* Bdst1 = (const short*)((const char*)Bs + wv * 2048 + 1024);

    int wr = wv >> 1, wc = wv & 1;
    int lrow = lane & 15, lhi = lane >> 4;
    int arow = wr * 64 + lrow, brow = wc * 64 + lrow;
    const short* ard = As + ((((arow * 64 + lhi * 16)) ^ ((lrow & 7) << 4)) >> 1);
    const short* brd = Bs + ((((brow * 64 + lhi * 16)) ^ ((lrow & 7) << 4)) >> 1);

    f32x4 zero = {0.f, 0.f, 0.f, 0.f};
    f32x4 acc[4][4];
    #pragma unroll
    for (int i = 0; i < 4; i++)
        #pragma unroll
        for (int j = 0; j < 4; j++) acc[i][j] = zero;

    for (int k0 = 0; k0 < CDIM; k0 += 32) {
        gl16(Ag0 + k0, Adst0);
        gl16(Bg0 + k0, Bdst0);
        gl16(Ag1 + k0, Adst1);
        gl16(Bg1 + k0, Bdst1);
        __syncthreads();
        bf16x8 af[4], bfr[4];
        #pragma unroll
        for (int t = 0; t < 4; t++) af[t]  = *(const bf16x8*)(ard + t * 512);
        #pragma unroll
        for (int t = 0; t < 4; t++) bfr[t] = *(const bf16x8*)(brd + t * 512);
        #pragma unroll
        for (int i = 0; i < 4; i++)
            #pragma unroll
            for (int j = 0; j < 4; j++)
                acc[i][j] = __builtin_amdgcn_mfma_f32_16x16x32_bf16(af[i], bfr[j], acc[i][j], 0, 0, 0);
        __syncthreads();
    }
    // epilogue: window reverse + unshift, fp32 out
    #pragma unroll
    for (int ti = 0; ti < 4; ti++) {
        #pragma unroll
        for (int r = 0; r < 4; r++) {
            int m = m0 + wr * 64 + ti * 16 + lhi * 4 + r;
            int b = m >> 12, wIdx = (m >> 6) & 63, tok = m & 63;
            int gh = ((wIdx >> 3) << 3) + (tok >> 3);
            int gw = (wIdx & 7) * 8 + (tok & 7);
            int ih = (gh + SHIFT_) & 63, iw = (gw + SHIFT_) & 63;
            size_t ob = ((size_t)(b << 12) + ih * 64 + iw) * CDIM;
            #pragma unroll
            for (int tj = 0; tj < 4; tj++) {
                int col = n0 + wc * 64 + tj * 16 + lrow;
                out[ob + col] = acc[ti][tj][r] + proj_b[col];
            }
        }
    }
}

extern "C" void kernel_launch(void* const* d_in, const int* in_sizes, int n_in,
                              void* d_out, int out_size, void* d_ws, size_t ws_size,
                              hipStream_t stream) {
    const float* x          = (const float*)d_in[0];
    const float* qkv_w      = (const float*)d_in[1];
    const float* qkv_b      = (const float*)d_in[2];
    const float* proj_w     = (const float*)d_in[3];
    const float* proj_b     = (const float*)d_in[4];
    const float* bias_table = (const float*)d_in[5];
    const int*   rel_index  = (const int*)d_in[6];
    float* out = (float*)d_out;
    char* ws = (char*)d_ws;

    short* qkvwt   = (short*)(ws);                 //  884736 B
    short* projwt  = (short*)(ws + 884736);        //  294912 B
    float* biasT   = (float*)(ws + 1179648);       //  196608 B
    short* attno   = (short*)(ws + 1376256);       //  100663296 B -> ~102 MB

    prep_kernel<<<1728, 256, 0, stream>>>(qkv_w, proj_w, bias_table, rel_index,
                                          qkvwt, projwt, biasT);
    fused_qa<<<2048, 256, 0, stream>>>(x, qkvwt, qkv_b, biasT, attno);
    gemm_proj<<<3072, 256, 0, stream>>>(attno, projwt, proj_b, out);
}

// Round 8
// 671.568 us; speedup vs baseline: 1.0561x; 1.0561x over previous
//
#include <hip/hip_runtime.h>
#include <hip/hip_bf16.h>

#define CDIM 384
#define NQKV 1152
#define HEADS 12
#define SHIFT_ 4
#define SCALE_Q 0.17677669529663687f  // 32^-0.5

typedef __attribute__((ext_vector_type(8))) short bf16x8;
typedef __attribute__((ext_vector_type(4))) float f32x4;
typedef __attribute__((ext_vector_type(4))) float float4_t;
typedef __attribute__((ext_vector_type(4))) unsigned u32x4;

__device__ inline short f2bf(float f) {
    union { float f; unsigned u; } v; v.f = f;
    unsigned r = v.u + 0x7FFFu + ((v.u >> 16) & 1u);
    return (short)(r >> 16);
}

__device__ inline unsigned cvtpk(float lo, float hi) {
    unsigned r;
    asm("v_cvt_pk_bf16_f32 %0, %1, %2" : "=v"(r) : "v"(lo), "v"(hi));
    return r;
}

__device__ inline bf16x8 mk8(unsigned w0, unsigned w1, unsigned w2, unsigned w3) {
    u32x4 t = {w0, w1, w2, w3};
    return __builtin_bit_cast(bf16x8, t);
}

// Regroup: two acc tiles (rows 0-15 from pairs p0,p1; rows 16-31 from p2,p3;
// per-lane col=lane&15, rows lhi*4+r packed as bf16 pairs) -> MFMA operand
// fragment (per-lane col=lane&15, rows lhi*8..lhi*8+7).
__device__ inline bf16x8 regroup(unsigned p0, unsigned p1, unsigned p2,
                                 unsigned p3, int lane) {
    int lhi = (lane >> 4) & 3;
    int s0 = (lane & 15) + ((lhi & 1) ? 32 : 0);
    int s1 = s0 + 16;
    unsigned a0 = __shfl(p0, s0), b0 = __shfl(p2, s0);
    unsigned a1 = __shfl(p1, s0), b1 = __shfl(p3, s0);
    unsigned a2 = __shfl(p0, s1), b2 = __shfl(p2, s1);
    unsigned a3 = __shfl(p1, s1), b3 = __shfl(p3, s1);
    bool hi = lhi >= 2;
    return mk8(hi ? b0 : a0, hi ? b1 : a1, hi ? b2 : a2, hi ? b3 : a3);
}

__device__ inline void gl16(const short* g, const short* l) {
    __builtin_amdgcn_global_load_lds((const __attribute__((address_space(1))) void*)g,
                                     (__attribute__((address_space(3))) void*)l, 16, 0, 0);
}

__device__ inline int invswz(int c) {
    int b2 = (c >> 2) & 1, b3 = (c >> 3) & 1, b4 = (c >> 4) & 1;
    return (c & ~7) | ((b2 ^ b4) << 2) | (((((c >> 1) & 1)) ^ b3) << 1) | ((c & 1) ^ b2 ^ b4);
}

// ---------------- prep: weight transpose->bf16, bias matrix (transposed) ---
__global__ void prep_kernel(const float* __restrict__ qkv_w,
                            const float* __restrict__ proj_w,
                            const float* __restrict__ bias_table,
                            const int* __restrict__ rel_index,
                            short* __restrict__ qkvwt,
                            short* __restrict__ projwt,
                            float* __restrict__ biasT) {
    int t = blockIdx.x * 256 + threadIdx.x;
    if (t < NQKV * CDIM) {             // qkvwt[n][k] = qkv_w[k][n]
        int n = t / CDIM, k = t - n * CDIM;
        qkvwt[t] = f2bf(qkv_w[k * NQKV + n]);
    }
    if (t < CDIM * CDIM) {             // projwt[n][k] = proj_w[k][n]
        int n = t / CDIM, k = t - n * CDIM;
        projwt[t] = f2bf(proj_w[k * CDIM + n]);
    }
    if (t < HEADS * 64 * 64) {         // biasT[h][key j][query i]
        int h = t >> 12, jq = t & 4095;
        int j = jq >> 6, i = jq & 63;
        biasT[t] = bias_table[rel_index[i * 64 + j] * HEADS + h];
    }
}

// ---------------- fused qkv + attention: one block per window --------------
// 4 waves, wave = 3 heads. Xs staged once (48K); Q/K/V/S/P entirely in
// registers (W-as-A + X-as-A MFMA layouts + shfl regroup). LDS = Xs + regbuf
// = 49408 B -> 3 blocks/CU (3 waves/SIMD) at VGPR<=170.
__global__ __launch_bounds__(256, 2) void fused_qa(
    const float* __restrict__ x, const short* __restrict__ qkvwt,
    const float* __restrict__ qkv_b, const float* __restrict__ biasT,
    short* __restrict__ attno)
{
    __shared__ __attribute__((aligned(16))) char smem[49408];
    char* xs = smem;                           // [64][384] bf16, XOR-swizzled
    int tid = threadIdx.x;
    int lane = tid & 63, wv = tid >> 6;
    int lrow = lane & 15, lhi = lane >> 4;
    int* regbuf = (int*)(smem + 49152);

    int hw = blockIdx.x;
    int w = (hw & 7) * 256 + (hw >> 3);        // XCD-chunked window id
    int b = w >> 6, wIdx = w & 63;
    bool needmask = ((wIdx >> 3) == 7) || ((wIdx & 7) == 7);

    if (tid < 64) {                            // shift-mask region ids
        int gh = ((wIdx >> 3) << 3) + (tid >> 3);
        int gw = (wIdx & 7) * 8 + (tid & 7);
        int rh = gh < 56 ? 0 : (gh < 60 ? 1 : 2);
        int rw = gw < 56 ? 0 : (gw < 60 ? 1 : 2);
        regbuf[tid] = rh * 3 + rw;
    }

    // ---- stage x window -> Xs (bf16, XOR-swizzled), once ----
    #pragma unroll
    for (int it = 0; it < 6; it++) {
        int c = it * 256 + tid;                // 1536 chunks of 16 floats
        int tok = c / 24, kc = (c - tok * 24) * 16;
        int gh = ((wIdx >> 3) << 3) + (tok >> 3);
        int gw = (wIdx & 7) * 8 + (tok & 7);
        int sh_ = (gh + SHIFT_) & 63, sw_ = (gw + SHIFT_) & 63;
        const float* src = x + (size_t)(b * 4096 + sh_ * 64 + sw_) * CDIM + kc;
        float4_t a0 = *(const float4_t*)(src);
        float4_t a1 = *(const float4_t*)(src + 4);
        float4_t a2 = *(const float4_t*)(src + 8);
        float4_t a3 = *(const float4_t*)(src + 12);
        bf16x8 w0, w1;
        #pragma unroll
        for (int i = 0; i < 4; i++) {
            w0[i] = f2bf(a0[i]); w0[4 + i] = f2bf(a1[i]);
            w1[i] = f2bf(a2[i]); w1[4 + i] = f2bf(a3[i]);
        }
        int base = tok * 768 + kc * 2, sw = (tok & 7) << 4;
        *(bf16x8*)(xs + (base ^ sw)) = w0;
        *(bf16x8*)(xs + ((base + 16) ^ sw)) = w1;
    }
    __syncthreads();                           // only block-wide barrier

    int aswz = (lrow & 7) << 4;
    f32x4 zero = {0.f, 0.f, 0.f, 0.f};

    int rq[4], rk[4][4];                       // region ids (query/key view)
    #pragma unroll
    for (int qt = 0; qt < 4; qt++) rq[qt] = regbuf[qt * 16 + lrow];
    #pragma unroll
    for (int kt = 0; kt < 4; kt++)
        #pragma unroll
        for (int r = 0; r < 4; r++) rk[kt][r] = regbuf[kt * 16 + lhi * 4 + r];

    for (int hi = 0; hi < 3; hi++) {
        int h = wv * 3 + hi;
        // ---- qkv GEMM: Q,K via W-as-A (acc col=token); V via X-as-A ----
        const short* wq0 = qkvwt + (size_t)(h * 32 + lrow) * CDIM + lhi * 8;
        const short* wq1 = wq0 + 16 * CDIM;
        const short* wk0 = qkvwt + (size_t)(CDIM + h * 32 + lrow) * CDIM + lhi * 8;
        const short* wk1 = wk0 + 16 * CDIM;
        const short* wv0 = qkvwt + (size_t)(2 * CDIM + h * 32 + lrow) * CDIM + lhi * 8;
        const short* wv1 = wv0 + 16 * CDIM;
        f32x4 aq[2][4], ak[2][4], av[4][2];
        #pragma unroll
        for (int i = 0; i < 4; i++) {
            aq[0][i] = zero; aq[1][i] = zero; ak[0][i] = zero; ak[1][i] = zero;
            av[i][0] = zero; av[i][1] = zero;
        }
        #pragma unroll
        for (int ks = 0; ks < 12; ks++) {
            bf16x8 fq0 = *(const bf16x8*)(wq0 + ks * 32);
            bf16x8 fq1 = *(const bf16x8*)(wq1 + ks * 32);
            bf16x8 fk0 = *(const bf16x8*)(wk0 + ks * 32);
            bf16x8 fk1 = *(const bf16x8*)(wk1 + ks * 32);
            bf16x8 fv0 = *(const bf16x8*)(wv0 + ks * 32);
            bf16x8 fv1 = *(const bf16x8*)(wv1 + ks * 32);
            bf16x8 xf[4];
            #pragma unroll
            for (int tt = 0; tt < 4; tt++)
                xf[tt] = *(const bf16x8*)(xs + (((tt * 16 + lrow) * 768 + ks * 64 + lhi * 16) ^ aswz));
            __builtin_amdgcn_s_setprio(1);
            #pragma unroll
            for (int tt = 0; tt < 4; tt++) {
                aq[0][tt] = __builtin_amdgcn_mfma_f32_16x16x32_bf16(fq0, xf[tt], aq[0][tt], 0, 0, 0);
                aq[1][tt] = __builtin_amdgcn_mfma_f32_16x16x32_bf16(fq1, xf[tt], aq[1][tt], 0, 0, 0);
                ak[0][tt] = __builtin_amdgcn_mfma_f32_16x16x32_bf16(fk0, xf[tt], ak[0][tt], 0, 0, 0);
                ak[1][tt] = __builtin_amdgcn_mfma_f32_16x16x32_bf16(fk1, xf[tt], ak[1][tt], 0, 0, 0);
                av[tt][0] = __builtin_amdgcn_mfma_f32_16x16x32_bf16(xf[tt], fv0, av[tt][0], 0, 0, 0);
                av[tt][1] = __builtin_amdgcn_mfma_f32_16x16x32_bf16(xf[tt], fv1, av[tt][1], 0, 0, 0);
            }
            __builtin_amdgcn_s_setprio(0);
        }
        // ---- V epilogue -> in-register B fragments (frees av) ----
        float bv0 = qkv_b[2 * CDIM + h * 32 + lrow];
        float bv1 = qkv_b[2 * CDIM + h * 32 + 16 + lrow];
        bf16x8 vfrag[2][2];
        #pragma unroll
        for (int ks2 = 0; ks2 < 2; ks2++) {
            #pragma unroll
            for (int dt = 0; dt < 2; dt++) {
                float bv = dt ? bv1 : bv0;
                unsigned p0 = cvtpk(av[2 * ks2][dt][0] + bv, av[2 * ks2][dt][1] + bv);
                unsigned p1 = cvtpk(av[2 * ks2][dt][2] + bv, av[2 * ks2][dt][3] + bv);
                unsigned p2 = cvtpk(av[2 * ks2 + 1][dt][0] + bv, av[2 * ks2 + 1][dt][1] + bv);
                unsigned p3 = cvtpk(av[2 * ks2 + 1][dt][2] + bv, av[2 * ks2 + 1][dt][3] + bv);
                vfrag[ks2][dt] = regroup(p0, p1, p2, p3, lane);
            }
        }
        // ---- Q/K epilogue -> fragments (bias, scale, pack, regroup) ----
        float bq[2][4], bk[2][4];
        #pragma unroll
        for (int dt = 0; dt < 2; dt++)
            #pragma unroll
            for (int r = 0; r < 4; r++) {
                bq[dt][r] = qkv_b[h * 32 + dt * 16 + lhi * 4 + r];
                bk[dt][r] = qkv_b[CDIM + h * 32 + dt * 16 + lhi * 4 + r];
            }
        bf16x8 qf[4], kf[4];
        #pragma unroll
        for (int tt = 0; tt < 4; tt++) {
            unsigned p0 = cvtpk((aq[0][tt][0] + bq[0][0]) * SCALE_Q, (aq[0][tt][1] + bq[0][1]) * SCALE_Q);
            unsigned p1 = cvtpk((aq[0][tt][2] + bq[0][2]) * SCALE_Q, (aq[0][tt][3] + bq[0][3]) * SCALE_Q);
            unsigned p2 = cvtpk((aq[1][tt][0] + bq[1][0]) * SCALE_Q, (aq[1][tt][1] + bq[1][1]) * SCALE_Q);
            unsigned p3 = cvtpk((aq[1][tt][2] + bq[1][2]) * SCALE_Q, (aq[1][tt][3] + bq[1][3]) * SCALE_Q);
            qf[tt] = regroup(p0, p1, p2, p3, lane);
            p0 = cvtpk(ak[0][tt][0] + bk[0][0], ak[0][tt][1] + bk[0][1]);
            p1 = cvtpk(ak[0][tt][2] + bk[0][2], ak[0][tt][3] + bk[0][3]);
            p2 = cvtpk(ak[1][tt][0] + bk[1][0], ak[1][tt][1] + bk[1][1]);
            p3 = cvtpk(ak[1][tt][2] + bk[1][2], ak[1][tt][3] + bk[1][3]);
            kf[tt] = regroup(p0, p1, p2, p3, lane);
        }
        // ---- S^T = K Q^T : rows=keys(lhi*4+r), cols=queries(lane&15) ----
        f32x4 st[4][4];
        __builtin_amdgcn_s_setprio(1);
        #pragma unroll
        for (int kt = 0; kt < 4; kt++)
            #pragma unroll
            for (int qt = 0; qt < 4; qt++)
                st[kt][qt] = __builtin_amdgcn_mfma_f32_16x16x32_bf16(kf[kt], qf[qt], zero, 0, 0, 0);
        __builtin_amdgcn_s_setprio(0);
        // ---- softmax per query (lane-local row) + P fragments ----
        const float* bT = biasT + h * 4096 + lrow;  // + key*64 + qt*16
        bf16x8 pa[4][2];
        #pragma unroll
        for (int qt = 0; qt < 4; qt++) {
            float pv[16]; float sum = 0.f;
            #pragma unroll
            for (int kt = 0; kt < 4; kt++)
                #pragma unroll
                for (int r = 0; r < 4; r++) {
                    float v = st[kt][qt][r] + bT[(kt * 16 + lhi * 4 + r) * 64 + qt * 16];
                    float p = __expf(v);
                    p = (needmask && (rq[qt] != rk[kt][r])) ? 0.f : p;
                    pv[kt * 4 + r] = p; sum += p;
                }
            sum += __shfl_xor(sum, 16);
            sum += __shfl_xor(sum, 32);
            float rcp = 1.0f / sum;
            unsigned a0 = cvtpk(pv[0] * rcp, pv[1] * rcp);
            unsigned a1 = cvtpk(pv[2] * rcp, pv[3] * rcp);
            unsigned a2 = cvtpk(pv[4] * rcp, pv[5] * rcp);
            unsigned a3 = cvtpk(pv[6] * rcp, pv[7] * rcp);
            pa[qt][0] = regroup(a0, a1, a2, a3, lane);
            a0 = cvtpk(pv[8] * rcp,  pv[9] * rcp);
            a1 = cvtpk(pv[10] * rcp, pv[11] * rcp);
            a2 = cvtpk(pv[12] * rcp, pv[13] * rcp);
            a3 = cvtpk(pv[14] * rcp, pv[15] * rcp);
            pa[qt][1] = regroup(a0, a1, a2, a3, lane);
        }
        // ---- PV: out[query][dim], V entirely in registers ----
        f32x4 ao[4][2];
        #pragma unroll
        for (int qt = 0; qt < 4; qt++) { ao[qt][0] = zero; ao[qt][1] = zero; }
        __builtin_amdgcn_s_setprio(1);
        #pragma unroll
        for (int ks2 = 0; ks2 < 2; ks2++)
            #pragma unroll
            for (int qt = 0; qt < 4; qt++) {
                ao[qt][0] = __builtin_amdgcn_mfma_f32_16x16x32_bf16(pa[qt][ks2], vfrag[ks2][0], ao[qt][0], 0, 0, 0);
                ao[qt][1] = __builtin_amdgcn_mfma_f32_16x16x32_bf16(pa[qt][ks2], vfrag[ks2][1], ao[qt][1], 0, 0, 0);
            }
        __builtin_amdgcn_s_setprio(0);
        // ---- direct bf16 stores (16-lane groups cover full 64B lines) ----
        short* abase = attno + (size_t)(w * 64) * CDIM + h * 32;
        #pragma unroll
        for (int qt = 0; qt < 4; qt++)
            #pragma unroll
            for (int dt = 0; dt < 2; dt++)
                #pragma unroll
                for (int r = 0; r < 4; r++) {
                    int token = qt * 16 + lhi * 4 + r;
                    abase[(size_t)token * CDIM + dt * 16 + lrow] = f2bf(ao[qt][dt][r]);
                }
    }
}

// ---------------- GEMM2: out = attno @ proj_w^T + b, window-reverse --------
__global__ __launch_bounds__(256) void gemm_proj(
    const short* __restrict__ a, const short* __restrict__ wt,
    const float* __restrict__ proj_b, float* __restrict__ out)
{
    __shared__ alignas(16) short As[4096];
    __shared__ alignas(16) short Bs[4096];
    int tid = threadIdx.x;
    int hw = blockIdx.x;                       // 3072 blocks, %8==0
    int lb = (hw & 7) * 384 + (hw >> 3);
    int bm = lb / 3, bn = lb - bm * 3;
    int m0 = bm * 128, n0 = bn * 128;

    int lane = tid & 63, wv = tid >> 6;
    int c0 = wv * 128 + lane, c1 = c0 + 64;
    int l0 = invswz(c0), l1 = invswz(c1);
    const short* Ag0 = a + (size_t)(m0 + (l0 >> 2)) * CDIM + (l0 & 3) * 8;
    const short* Ag1 = a + (size_t)(m0 + (l1 >> 2)) * CDIM + (l1 & 3) * 8;
    const short* Bg0 = wt + (size_t)(n0 + (l0 >> 2)) * CDIM + (l0 & 3) * 8;
    const short* Bg1 = wt + (size_t)(n0 + (l1 >> 2)) * CDIM + (l1 & 3) * 8;
    const short* Adst0 = (const short*)((const char*)As + wv * 2048);
    const short* Adst1 = (const short*)((const char*)As + wv * 2048 + 1024);
    const short* Bdst0 = (const short*)((const char*)Bs + wv * 2048);
    const short* Bdst1 = (const short*)((const char*)Bs + wv * 2048 + 1024);

    int wr = wv >> 1, wc = wv & 1;
    int lrow = lane & 15, lhi = lane >> 4;
    int arow = wr * 64 + lrow, brow = wc * 64 + lrow;
    const short* ard = As + ((((arow * 64 + lhi * 16)) ^ ((lrow & 7) << 4)) >> 1);
    const short* brd = Bs + ((((brow * 64 + lhi * 16)) ^ ((lrow & 7) << 4)) >> 1);

    f32x4 zero = {0.f, 0.f, 0.f, 0.f};
    f32x4 acc[4][4];
    #pragma unroll
    for (int i = 0; i < 4; i++)
        #pragma unroll
        for (int j = 0; j < 4; j++) acc[i][j] = zero;

    for (int k0 = 0; k0 < CDIM; k0 += 32) {
        gl16(Ag0 + k0, Adst0);
        gl16(Bg0 + k0, Bdst0);
        gl16(Ag1 + k0, Adst1);
        gl16(Bg1 + k0, Bdst1);
        __syncthreads();
        bf16x8 af[4], bfr[4];
        #pragma unroll
        for (int t = 0; t < 4; t++) af[t]  = *(const bf16x8*)(ard + t * 512);
        #pragma unroll
        for (int t = 0; t < 4; t++) bfr[t] = *(const bf16x8*)(brd + t * 512);
        #pragma unroll
        for (int i = 0; i < 4; i++)
            #pragma unroll
            for (int j = 0; j < 4; j++)
                acc[i][j] = __builtin_amdgcn_mfma_f32_16x16x32_bf16(af[i], bfr[j], acc[i][j], 0, 0, 0);
        __syncthreads();
    }
    // epilogue: window reverse + unshift, fp32 out
    #pragma unroll
    for (int ti = 0; ti < 4; ti++) {
        #pragma unroll
        for (int r = 0; r < 4; r++) {
            int m = m0 + wr * 64 + ti * 16 + lhi * 4 + r;
            int b = m >> 12, wIdx = (m >> 6) & 63, tok = m & 63;
            int gh = ((wIdx >> 3) << 3) + (tok >> 3);
            int gw = (wIdx & 7) * 8 + (tok & 7);
            int ih = (gh + SHIFT_) & 63, iw = (gw + SHIFT_) & 63;
            size_t ob = ((size_t)(b << 12) + ih * 64 + iw) * CDIM;
            #pragma unroll
            for (int tj = 0; tj < 4; tj++) {
                int col = n0 + wc * 64 + tj * 16 + lrow;
                out[ob + col] = acc[ti][tj][r] + proj_b[col];
            }
        }
    }
}

extern "C" void kernel_launch(void* const* d_in, const int* in_sizes, int n_in,
                              void* d_out, int out_size, void* d_ws, size_t ws_size,
                              hipStream_t stream) {
    const float* x          = (const float*)d_in[0];
    const float* qkv_w      = (const float*)d_in[1];
    const float* qkv_b      = (const float*)d_in[2];
    const float* proj_w     = (const float*)d_in[3];
    const float* proj_b     = (const float*)d_in[4];
    const float* bias_table = (const float*)d_in[5];
    const int*   rel_index  = (const int*)d_in[6];
    float* out = (float*)d_out;
    char* ws = (char*)d_ws;

    short* qkvwt   = (short*)(ws);                 //  884736 B
    short* projwt  = (short*)(ws + 884736);        //  294912 B
    float* biasT   = (float*)(ws + 1179648);       //  196608 B
    short* attno   = (short*)(ws + 1376256);       //  100663296 B -> ~102 MB

    prep_kernel<<<1728, 256, 0, stream>>>(qkv_w, proj_w, bias_table, rel_index,
                                          qkvwt, projwt, biasT);
    fused_qa<<<2048, 256, 0, stream>>>(x, qkvwt, qkv_b, biasT, attno);
    gemm_proj<<<3072, 256, 0, stream>>>(attno, projwt, proj_b, out);
}

// Round 9
// 596.235 us; speedup vs baseline: 1.1896x; 1.1263x over previous
//
#include <hip/hip_runtime.h>
#include <hip/hip_bf16.h>

#define CDIM 384
#define NQKV 1152
#define HEADS 12
#define SHIFT_ 4
#define SCALE_Q 0.17677669529663687f  // 32^-0.5

typedef __attribute__((ext_vector_type(8))) short bf16x8;
typedef __attribute__((ext_vector_type(4))) float f32x4;
typedef __attribute__((ext_vector_type(4))) float float4_t;
typedef __attribute__((ext_vector_type(4))) unsigned u32x4;
typedef __attribute__((ext_vector_type(2))) unsigned u32x2;

__device__ inline short f2bf(float f) {
    union { float f; unsigned u; } v; v.f = f;
    unsigned r = v.u + 0x7FFFu + ((v.u >> 16) & 1u);
    return (short)(r >> 16);
}

__device__ inline unsigned cvtpk(float lo, float hi) {
    unsigned r;
    asm("v_cvt_pk_bf16_f32 %0, %1, %2" : "=v"(r) : "v"(lo), "v"(hi));
    return r;
}

__device__ inline bf16x8 mk8(unsigned w0, unsigned w1, unsigned w2, unsigned w3) {
    u32x4 t = {w0, w1, w2, w3};
    return __builtin_bit_cast(bf16x8, t);
}

// Regroup: two acc tiles (rows 0-15 from pairs p0,p1; rows 16-31 from p2,p3;
// per-lane col=lane&15, rows lhi*4+r packed as bf16 pairs) -> MFMA operand
// fragment (per-lane col slot=lane&15, k=lhi*8..lhi*8+7).
__device__ inline bf16x8 regroup(unsigned p0, unsigned p1, unsigned p2,
                                 unsigned p3, int lane) {
    int lhi = (lane >> 4) & 3;
    int s0 = (lane & 15) + ((lhi & 1) ? 32 : 0);
    int s1 = s0 + 16;
    unsigned a0 = __shfl(p0, s0), b0 = __shfl(p2, s0);
    unsigned a1 = __shfl(p1, s0), b1 = __shfl(p3, s0);
    unsigned a2 = __shfl(p0, s1), b2 = __shfl(p2, s1);
    unsigned a3 = __shfl(p1, s1), b3 = __shfl(p3, s1);
    bool hi = lhi >= 2;
    return mk8(hi ? b0 : a0, hi ? b1 : a1, hi ? b2 : a2, hi ? b3 : a3);
}

__device__ inline void gl16(const short* g, const short* l) {
    __builtin_amdgcn_global_load_lds((const __attribute__((address_space(1))) void*)g,
                                     (__attribute__((address_space(3))) void*)l, 16, 0, 0);
}

__device__ inline int invswz(int c) {
    int b2 = (c >> 2) & 1, b3 = (c >> 3) & 1, b4 = (c >> 4) & 1;
    return (c & ~7) | ((b2 ^ b4) << 2) | (((((c >> 1) & 1)) ^ b3) << 1) | ((c & 1) ^ b2 ^ b4);
}

// ---------------- prep: weight transpose->bf16, bias matrix (transposed) ---
__global__ void prep_kernel(const float* __restrict__ qkv_w,
                            const float* __restrict__ proj_w,
                            const float* __restrict__ bias_table,
                            const int* __restrict__ rel_index,
                            short* __restrict__ qkvwt,
                            short* __restrict__ projwt,
                            float* __restrict__ biasT) {
    int t = blockIdx.x * 256 + threadIdx.x;
    if (t < NQKV * CDIM) {             // qkvwt[n][k] = qkv_w[k][n]
        int n = t / CDIM, k = t - n * CDIM;
        qkvwt[t] = f2bf(qkv_w[k * NQKV + n]);
    }
    if (t < CDIM * CDIM) {             // projwt[n][k] = proj_w[k][n]
        int n = t / CDIM, k = t - n * CDIM;
        projwt[t] = f2bf(proj_w[k * CDIM + n]);
    }
    if (t < HEADS * 64 * 64) {         // biasT[h][key j][query i]
        int h = t >> 12, jq = t & 4095;
        int j = jq >> 6, i = jq & 63;
        biasT[t] = bias_table[rel_index[i * 64 + j] * HEADS + h];
    }
}

// ---------------- fused qkv + attention: one block per window --------------
// 4 waves, wave = 3 heads. Xs staged once (48K, NT loads); Q/K/V/S/P in
// registers. PV computed transposed (mfma(vfrag,pa)) so each lane holds 4
// consecutive dims -> paired 8B NT stores cover full 64B lines.
__global__ __launch_bounds__(256, 2) void fused_qa(
    const float* __restrict__ x, const short* __restrict__ qkvwt,
    const float* __restrict__ qkv_b, const float* __restrict__ biasT,
    short* __restrict__ attno)
{
    __shared__ __attribute__((aligned(16))) char smem[49408];
    char* xs = smem;                           // [64][384] bf16, XOR-swizzled
    int tid = threadIdx.x;
    int lane = tid & 63, wv = tid >> 6;
    int lrow = lane & 15, lhi = lane >> 4;
    int* regbuf = (int*)(smem + 49152);

    int hw = blockIdx.x;
    int w = (hw & 7) * 256 + (hw >> 3);        // XCD-chunked window id
    int b = w >> 6, wIdx = w & 63;
    bool needmask = ((wIdx >> 3) == 7) || ((wIdx & 7) == 7);

    if (tid < 64) {                            // shift-mask region ids
        int gh = ((wIdx >> 3) << 3) + (tid >> 3);
        int gw = (wIdx & 7) * 8 + (tid & 7);
        int rh = gh < 56 ? 0 : (gh < 60 ? 1 : 2);
        int rw = gw < 56 ? 0 : (gw < 60 ? 1 : 2);
        regbuf[tid] = rh * 3 + rw;
    }

    // ---- stage x window -> Xs (bf16, XOR-swizzled), once; NT loads ----
    #pragma unroll
    for (int it = 0; it < 6; it++) {
        int c = it * 256 + tid;                // 1536 chunks of 16 floats
        int tok = c / 24, kc = (c - tok * 24) * 16;
        int gh = ((wIdx >> 3) << 3) + (tok >> 3);
        int gw = (wIdx & 7) * 8 + (tok & 7);
        int sh_ = (gh + SHIFT_) & 63, sw_ = (gw + SHIFT_) & 63;
        const float* src = x + (size_t)(b * 4096 + sh_ * 64 + sw_) * CDIM + kc;
        float4_t a0 = __builtin_nontemporal_load((const float4_t*)(src));
        float4_t a1 = __builtin_nontemporal_load((const float4_t*)(src + 4));
        float4_t a2 = __builtin_nontemporal_load((const float4_t*)(src + 8));
        float4_t a3 = __builtin_nontemporal_load((const float4_t*)(src + 12));
        bf16x8 w0, w1;
        #pragma unroll
        for (int i = 0; i < 4; i++) {
            w0[i] = f2bf(a0[i]); w0[4 + i] = f2bf(a1[i]);
            w1[i] = f2bf(a2[i]); w1[4 + i] = f2bf(a3[i]);
        }
        int base = tok * 768 + kc * 2, sw = (tok & 7) << 4;
        *(bf16x8*)(xs + (base ^ sw)) = w0;
        *(bf16x8*)(xs + ((base + 16) ^ sw)) = w1;
    }
    __syncthreads();                           // only block-wide barrier

    int aswz = (lrow & 7) << 4;
    f32x4 zero = {0.f, 0.f, 0.f, 0.f};

    int rq[4], rk[4][4];                       // region ids (query/key view)
    #pragma unroll
    for (int qt = 0; qt < 4; qt++) rq[qt] = regbuf[qt * 16 + lrow];
    #pragma unroll
    for (int kt = 0; kt < 4; kt++)
        #pragma unroll
        for (int r = 0; r < 4; r++) rk[kt][r] = regbuf[kt * 16 + lhi * 4 + r];

    for (int hi = 0; hi < 3; hi++) {
        int h = wv * 3 + hi;
        // ---- qkv GEMM: Q,K via W-as-A (acc col=token); V via X-as-A ----
        const short* wq0 = qkvwt + (size_t)(h * 32 + lrow) * CDIM + lhi * 8;
        const short* wq1 = wq0 + 16 * CDIM;
        const short* wk0 = qkvwt + (size_t)(CDIM + h * 32 + lrow) * CDIM + lhi * 8;
        const short* wk1 = wk0 + 16 * CDIM;
        const short* wv0 = qkvwt + (size_t)(2 * CDIM + h * 32 + lrow) * CDIM + lhi * 8;
        const short* wv1 = wv0 + 16 * CDIM;
        f32x4 aq[2][4], ak[2][4], av[4][2];
        #pragma unroll
        for (int i = 0; i < 4; i++) {
            aq[0][i] = zero; aq[1][i] = zero; ak[0][i] = zero; ak[1][i] = zero;
            av[i][0] = zero; av[i][1] = zero;
        }
        #pragma unroll
        for (int ks = 0; ks < 12; ks++) {
            bf16x8 fq0 = *(const bf16x8*)(wq0 + ks * 32);
            bf16x8 fq1 = *(const bf16x8*)(wq1 + ks * 32);
            bf16x8 fk0 = *(const bf16x8*)(wk0 + ks * 32);
            bf16x8 fk1 = *(const bf16x8*)(wk1 + ks * 32);
            bf16x8 fv0 = *(const bf16x8*)(wv0 + ks * 32);
            bf16x8 fv1 = *(const bf16x8*)(wv1 + ks * 32);
            bf16x8 xf[4];
            #pragma unroll
            for (int tt = 0; tt < 4; tt++)
                xf[tt] = *(const bf16x8*)(xs + (((tt * 16 + lrow) * 768 + ks * 64 + lhi * 16) ^ aswz));
            __builtin_amdgcn_s_setprio(1);
            #pragma unroll
            for (int tt = 0; tt < 4; tt++) {
                aq[0][tt] = __builtin_amdgcn_mfma_f32_16x16x32_bf16(fq0, xf[tt], aq[0][tt], 0, 0, 0);
                aq[1][tt] = __builtin_amdgcn_mfma_f32_16x16x32_bf16(fq1, xf[tt], aq[1][tt], 0, 0, 0);
                ak[0][tt] = __builtin_amdgcn_mfma_f32_16x16x32_bf16(fk0, xf[tt], ak[0][tt], 0, 0, 0);
                ak[1][tt] = __builtin_amdgcn_mfma_f32_16x16x32_bf16(fk1, xf[tt], ak[1][tt], 0, 0, 0);
                av[tt][0] = __builtin_amdgcn_mfma_f32_16x16x32_bf16(xf[tt], fv0, av[tt][0], 0, 0, 0);
                av[tt][1] = __builtin_amdgcn_mfma_f32_16x16x32_bf16(xf[tt], fv1, av[tt][1], 0, 0, 0);
            }
            __builtin_amdgcn_s_setprio(0);
        }
        // ---- V epilogue -> in-register B fragments (frees av) ----
        float bv0 = qkv_b[2 * CDIM + h * 32 + lrow];
        float bv1 = qkv_b[2 * CDIM + h * 32 + 16 + lrow];
        bf16x8 vfrag[2][2];
        #pragma unroll
        for (int ks2 = 0; ks2 < 2; ks2++) {
            #pragma unroll
            for (int dt = 0; dt < 2; dt++) {
                float bv = dt ? bv1 : bv0;
                unsigned p0 = cvtpk(av[2 * ks2][dt][0] + bv, av[2 * ks2][dt][1] + bv);
                unsigned p1 = cvtpk(av[2 * ks2][dt][2] + bv, av[2 * ks2][dt][3] + bv);
                unsigned p2 = cvtpk(av[2 * ks2 + 1][dt][0] + bv, av[2 * ks2 + 1][dt][1] + bv);
                unsigned p3 = cvtpk(av[2 * ks2 + 1][dt][2] + bv, av[2 * ks2 + 1][dt][3] + bv);
                vfrag[ks2][dt] = regroup(p0, p1, p2, p3, lane);
            }
        }
        // ---- Q/K epilogue -> fragments (bias, scale, pack, regroup) ----
        float bq[2][4], bk[2][4];
        #pragma unroll
        for (int dt = 0; dt < 2; dt++)
            #pragma unroll
            for (int r = 0; r < 4; r++) {
                bq[dt][r] = qkv_b[h * 32 + dt * 16 + lhi * 4 + r];
                bk[dt][r] = qkv_b[CDIM + h * 32 + dt * 16 + lhi * 4 + r];
            }
        bf16x8 qf[4], kf[4];
        #pragma unroll
        for (int tt = 0; tt < 4; tt++) {
            unsigned p0 = cvtpk((aq[0][tt][0] + bq[0][0]) * SCALE_Q, (aq[0][tt][1] + bq[0][1]) * SCALE_Q);
            unsigned p1 = cvtpk((aq[0][tt][2] + bq[0][2]) * SCALE_Q, (aq[0][tt][3] + bq[0][3]) * SCALE_Q);
            unsigned p2 = cvtpk((aq[1][tt][0] + bq[1][0]) * SCALE_Q, (aq[1][tt][1] + bq[1][1]) * SCALE_Q);
            unsigned p3 = cvtpk((aq[1][tt][2] + bq[1][2]) * SCALE_Q, (aq[1][tt][3] + bq[1][3]) * SCALE_Q);
            qf[tt] = regroup(p0, p1, p2, p3, lane);
            p0 = cvtpk(ak[0][tt][0] + bk[0][0], ak[0][tt][1] + bk[0][1]);
            p1 = cvtpk(ak[0][tt][2] + bk[0][2], ak[0][tt][3] + bk[0][3]);
            p2 = cvtpk(ak[1][tt][0] + bk[1][0], ak[1][tt][1] + bk[1][1]);
            p3 = cvtpk(ak[1][tt][2] + bk[1][2], ak[1][tt][3] + bk[1][3]);
            kf[tt] = regroup(p0, p1, p2, p3, lane);
        }
        // ---- S^T = K Q^T : rows=keys(lhi*4+r), cols=queries(lane&15) ----
        f32x4 st[4][4];
        __builtin_amdgcn_s_setprio(1);
        #pragma unroll
        for (int kt = 0; kt < 4; kt++)
            #pragma unroll
            for (int qt = 0; qt < 4; qt++)
                st[kt][qt] = __builtin_amdgcn_mfma_f32_16x16x32_bf16(kf[kt], qf[qt], zero, 0, 0, 0);
        __builtin_amdgcn_s_setprio(0);
        // ---- softmax per query (lane-local row) + P fragments ----
        const float* bT = biasT + h * 4096 + lrow;  // + key*64 + qt*16
        bf16x8 pa[4][2];
        #pragma unroll
        for (int qt = 0; qt < 4; qt++) {
            float pv[16]; float sum = 0.f;
            #pragma unroll
            for (int kt = 0; kt < 4; kt++)
                #pragma unroll
                for (int r = 0; r < 4; r++) {
                    float v = st[kt][qt][r] + bT[(kt * 16 + lhi * 4 + r) * 64 + qt * 16];
                    float p = __expf(v);
                    p = (needmask && (rq[qt] != rk[kt][r])) ? 0.f : p;
                    pv[kt * 4 + r] = p; sum += p;
                }
            sum += __shfl_xor(sum, 16);
            sum += __shfl_xor(sum, 32);
            float rcp = 1.0f / sum;
            unsigned a0 = cvtpk(pv[0] * rcp, pv[1] * rcp);
            unsigned a1 = cvtpk(pv[2] * rcp, pv[3] * rcp);
            unsigned a2 = cvtpk(pv[4] * rcp, pv[5] * rcp);
            unsigned a3 = cvtpk(pv[6] * rcp, pv[7] * rcp);
            pa[qt][0] = regroup(a0, a1, a2, a3, lane);
            a0 = cvtpk(pv[8] * rcp,  pv[9] * rcp);
            a1 = cvtpk(pv[10] * rcp, pv[11] * rcp);
            a2 = cvtpk(pv[12] * rcp, pv[13] * rcp);
            a3 = cvtpk(pv[14] * rcp, pv[15] * rcp);
            pa[qt][1] = regroup(a0, a1, a2, a3, lane);
        }
        // ---- PV transposed: ao2[qt][dt] = V^T P^T ----
        // acc: col(lane&15)=query, row(lhi*4+r)=dim dt*16+lhi*4+r
        f32x4 ao2[4][2];
        #pragma unroll
        for (int qt = 0; qt < 4; qt++) { ao2[qt][0] = zero; ao2[qt][1] = zero; }
        __builtin_amdgcn_s_setprio(1);
        #pragma unroll
        for (int ks2 = 0; ks2 < 2; ks2++)
            #pragma unroll
            for (int qt = 0; qt < 4; qt++) {
                ao2[qt][0] = __builtin_amdgcn_mfma_f32_16x16x32_bf16(vfrag[ks2][0], pa[qt][ks2], ao2[qt][0], 0, 0, 0);
                ao2[qt][1] = __builtin_amdgcn_mfma_f32_16x16x32_bf16(vfrag[ks2][1], pa[qt][ks2], ao2[qt][1], 0, 0, 0);
            }
        __builtin_amdgcn_s_setprio(0);
        // ---- stores: lane holds 4 consecutive dims -> paired 8B NT stores
        //      (dt=0,1 adjacent cover the full 64B (token,head) line) ----
        short* abase = attno + (size_t)(w * 64) * CDIM + h * 32 + lhi * 4;
        #pragma unroll
        for (int qt = 0; qt < 4; qt++) {
            int token = qt * 16 + lrow;
            short* p0 = abase + (size_t)token * CDIM;
            u32x2 s0, s1;
            s0[0] = cvtpk(ao2[qt][0][0], ao2[qt][0][1]);
            s0[1] = cvtpk(ao2[qt][0][2], ao2[qt][0][3]);
            s1[0] = cvtpk(ao2[qt][1][0], ao2[qt][1][1]);
            s1[1] = cvtpk(ao2[qt][1][2], ao2[qt][1][3]);
            __builtin_nontemporal_store(s0, (u32x2*)(p0));
            __builtin_nontemporal_store(s1, (u32x2*)(p0 + 16));
        }
    }
}

// ---------------- GEMM2: out = attno @ proj_w^T + b, window-reverse --------
__global__ __launch_bounds__(256) void gemm_proj(
    const short* __restrict__ a, const short* __restrict__ wt,
    const float* __restrict__ proj_b, float* __restrict__ out)
{
    __shared__ alignas(16) short As[4096];
    __shared__ alignas(16) short Bs[4096];
    int tid = threadIdx.x;
    int hw = blockIdx.x;                       // 3072 blocks, %8==0
    int lb = (hw & 7) * 384 + (hw >> 3);
    int bm = lb / 3, bn = lb - bm * 3;
    int m0 = bm * 128, n0 = bn * 128;

    int lane = tid & 63, wv = tid >> 6;
    int c0 = wv * 128 + lane, c1 = c0 + 64;
    int l0 = invswz(c0), l1 = invswz(c1);
    const short* Ag0 = a + (size_t)(m0 + (l0 >> 2)) * CDIM + (l0 & 3) * 8;
    const short* Ag1 = a + (size_t)(m0 + (l1 >> 2)) * CDIM + (l1 & 3) * 8;
    const short* Bg0 = wt + (size_t)(n0 + (l0 >> 2)) * CDIM + (l0 & 3) * 8;
    const short* Bg1 = wt + (size_t)(n0 + (l1 >> 2)) * CDIM + (l1 & 3) * 8;
    const short* Adst0 = (const short*)((const char*)As + wv * 2048);
    const short* Adst1 = (const short*)((const char*)As + wv * 2048 + 1024);
    const short* Bdst0 = (const short*)((const char*)Bs + wv * 2048);
    const short* Bdst1 = (const short*)((const char*)Bs + wv * 2048 + 1024);

    int wr = wv >> 1, wc = wv & 1;
    int lrow = lane & 15, lhi = lane >> 4;
    int arow = wr * 64 + lrow, brow = wc * 64 + lrow;
    const short* ard = As + ((((arow * 64 + lhi * 16)) ^ ((lrow & 7) << 4)) >> 1);
    const short* brd = Bs + ((((brow * 64 + lhi * 16)) ^ ((lrow & 7) << 4)) >> 1);

    f32x4 zero = {0.f, 0.f, 0.f, 0.f};
    f32x4 acc[4][4];
    #pragma unroll
    for (int i = 0; i < 4; i++)
        #pragma unroll
        for (int j = 0; j < 4; j++) acc[i][j] = zero;

    for (int k0 = 0; k0 < CDIM; k0 += 32) {
        gl16(Ag0 + k0, Adst0);
        gl16(Bg0 + k0, Bdst0);
        gl16(Ag1 + k0, Adst1);
        gl16(Bg1 + k0, Bdst1);
        __syncthreads();
        bf16x8 af[4], bfr[4];
        #pragma unroll
        for (int t = 0; t < 4; t++) af[t]  = *(const bf16x8*)(ard + t * 512);
        #pragma unroll
        for (int t = 0; t < 4; t++) bfr[t] = *(const bf16x8*)(brd + t * 512);
        #pragma unroll
        for (int i = 0; i < 4; i++)
            #pragma unroll
            for (int j = 0; j < 4; j++)
                acc[i][j] = __builtin_amdgcn_mfma_f32_16x16x32_bf16(af[i], bfr[j], acc[i][j], 0, 0, 0);
        __syncthreads();
    }
    // epilogue: window reverse + unshift, fp32 NT out
    #pragma unroll
    for (int ti = 0; ti < 4; ti++) {
        #pragma unroll
        for (int r = 0; r < 4; r++) {
            int m = m0 + wr * 64 + ti * 16 + lhi * 4 + r;
            int b = m >> 12, wIdx = (m >> 6) & 63, tok = m & 63;
            int gh = ((wIdx >> 3) << 3) + (tok >> 3);
            int gw = (wIdx & 7) * 8 + (tok & 7);
            int ih = (gh + SHIFT_) & 63, iw = (gw + SHIFT_) & 63;
            size_t ob = ((size_t)(b << 12) + ih * 64 + iw) * CDIM;
            #pragma unroll
            for (int tj = 0; tj < 4; tj++) {
                int col = n0 + wc * 64 + tj * 16 + lrow;
                float v = acc[ti][tj][r] + proj_b[col];
                __builtin_nontemporal_store(v, &out[ob + col]);
            }
        }
    }
}

extern "C" void kernel_launch(void* const* d_in, const int* in_sizes, int n_in,
                              void* d_out, int out_size, void* d_ws, size_t ws_size,
                              hipStream_t stream) {
    const float* x          = (const float*)d_in[0];
    const float* qkv_w      = (const float*)d_in[1];
    const float* qkv_b      = (const float*)d_in[2];
    const float* proj_w     = (const float*)d_in[3];
    const float* proj_b     = (const float*)d_in[4];
    const float* bias_table = (const float*)d_in[5];
    const int*   rel_index  = (const int*)d_in[6];
    float* out = (float*)d_out;
    char* ws = (char*)d_ws;

    short* qkvwt   = (short*)(ws);                 //  884736 B
    short* projwt  = (short*)(ws + 884736);        //  294912 B
    float* biasT   = (float*)(ws + 1179648);       //  196608 B
    short* attno   = (short*)(ws + 1376256);       //  100663296 B -> ~102 MB

    prep_kernel<<<1728, 256, 0, stream>>>(qkv_w, proj_w, bias_table, rel_index,
                                          qkvwt, projwt, biasT);
    fused_qa<<<2048, 256, 0, stream>>>(x, qkvwt, qkv_b, biasT, attno);
    gemm_proj<<<3072, 256, 0, stream>>>(attno, projwt, proj_b, out);
}

// Round 10
// 497.781 us; speedup vs baseline: 1.4248x; 1.1978x over previous
//
#include <hip/hip_runtime.h>
#include <hip/hip_bf16.h>

#define CDIM 384
#define NQKV 1152
#define HEADS 12
#define SHIFT_ 4
#define SCALE_Q 0.17677669529663687f  // 32^-0.5

typedef __attribute__((ext_vector_type(8))) short bf16x8;
typedef __attribute__((ext_vector_type(4))) float f32x4;
typedef __attribute__((ext_vector_type(4))) float float4_t;
typedef __attribute__((ext_vector_type(4))) unsigned u32x4;
typedef __attribute__((ext_vector_type(2))) unsigned u32x2;

__device__ inline short f2bf(float f) {
    union { float f; unsigned u; } v; v.f = f;
    unsigned r = v.u + 0x7FFFu + ((v.u >> 16) & 1u);
    return (short)(r >> 16);
}

__device__ inline unsigned cvtpk(float lo, float hi) {
    unsigned r;
    asm("v_cvt_pk_bf16_f32 %0, %1, %2" : "=v"(r) : "v"(lo), "v"(hi));
    return r;
}

__device__ inline bf16x8 mk8(unsigned w0, unsigned w1, unsigned w2, unsigned w3) {
    u32x4 t = {w0, w1, w2, w3};
    return __builtin_bit_cast(bf16x8, t);
}

// Regroup: two acc tiles (rows 0-15 as pairs p0,p1; rows 16-31 as p2,p3;
// per-lane col=lane&15, rows lhi*4+r) -> MFMA operand fragment
// (per-lane col slot=lane&15, k=lhi*8..lhi*8+7).  [R9-verified]
__device__ inline bf16x8 regroup(unsigned p0, unsigned p1, unsigned p2,
                                 unsigned p3, int lane) {
    int lhi = (lane >> 4) & 3;
    int s0 = (lane & 15) + ((lhi & 1) ? 32 : 0);
    int s1 = s0 + 16;
    unsigned a0 = __shfl(p0, s0), b0 = __shfl(p2, s0);
    unsigned a1 = __shfl(p1, s0), b1 = __shfl(p3, s0);
    unsigned a2 = __shfl(p0, s1), b2 = __shfl(p2, s1);
    unsigned a3 = __shfl(p1, s1), b3 = __shfl(p3, s1);
    bool hi = lhi >= 2;
    return mk8(hi ? b0 : a0, hi ? b1 : a1, hi ? b2 : a2, hi ? b3 : a3);
}

__device__ inline void gl16(const short* g, const short* l) {
    __builtin_amdgcn_global_load_lds((const __attribute__((address_space(1))) void*)g,
                                     (__attribute__((address_space(3))) void*)l, 16, 0, 0);
}

__device__ inline int invswz(int c) {
    int b2 = (c >> 2) & 1, b3 = (c >> 3) & 1, b4 = (c >> 4) & 1;
    return (c & ~7) | ((b2 ^ b4) << 2) | (((((c >> 1) & 1)) ^ b3) << 1) | ((c & 1) ^ b2 ^ b4);
}

__device__ inline int region_id(int wIdx, int tok) {
    int gh = ((wIdx >> 3) << 3) + (tok >> 3);
    int gw = (wIdx & 7) * 8 + (tok & 7);
    int rh = gh < 56 ? 0 : (gh < 60 ? 1 : 2);
    int rw = gw < 56 ? 0 : (gw < 60 ? 1 : 2);
    return rh * 3 + rw;
}

// ---------------- prep: weight transpose->bf16, bias in acc layout ---------
__global__ void prep_kernel(const float* __restrict__ qkv_w,
                            const float* __restrict__ proj_w,
                            const float* __restrict__ bias_table,
                            const int* __restrict__ rel_index,
                            short* __restrict__ qkvwt,
                            short* __restrict__ projwt,
                            float* __restrict__ biasP) {
    int t = blockIdx.x * 256 + threadIdx.x;
    if (t < NQKV * CDIM) {             // qkvwt[n][k] = qkv_w[k][n]
        int n = t / CDIM, k = t - n * CDIM;
        qkvwt[t] = f2bf(qkv_w[k * NQKV + n]);
    }
    if (t < CDIM * CDIM) {             // projwt[n][k] = proj_w[k][n]
        int n = t / CDIM, k = t - n * CDIM;
        projwt[t] = f2bf(proj_w[k * CDIM + n]);
    }
    if (t < HEADS * 16 * 64 * 4) {     // biasP[h][kt*4+qt][lane][r]
        int r = t & 3, lane = (t >> 2) & 63, g = (t >> 8) & 15, h = t >> 12;
        int kt = g >> 2, qt = g & 3;
        int key = kt * 16 + (lane >> 4) * 4 + r;
        int query = qt * 16 + (lane & 15);
        biasP[t] = bias_table[rel_index[query * 64 + key] * HEADS + h];
    }
}

// ---------------- xwin: shift + window partition + fp32->bf16 --------------
__global__ __launch_bounds__(256) void xwin_kernel(const float* __restrict__ x,
                                                   short* __restrict__ xw) {
    int t = blockIdx.x * 256 + threadIdx.x;    // one thread = 8 elements
    int mg = t / 48;
    int col = (t - mg * 48) * 8;
    int tok = mg & 63, win = mg >> 6;
    int b = win >> 6, wIdx = win & 63;
    int gh = ((wIdx >> 3) << 3) + (tok >> 3);
    int gw = (wIdx & 7) * 8 + (tok & 7);
    int sh_ = (gh + SHIFT_) & 63, sw_ = (gw + SHIFT_) & 63;
    const float* src = x + (size_t)(b * 4096 + sh_ * 64 + sw_) * CDIM + col;
    float4_t a0 = __builtin_nontemporal_load((const float4_t*)src);
    float4_t a1 = __builtin_nontemporal_load((const float4_t*)(src + 4));
    bf16x8 o;
    #pragma unroll
    for (int i = 0; i < 4; i++) { o[i] = f2bf(a0[i]); o[4 + i] = f2bf(a1[i]); }
    __builtin_nontemporal_store(o, (bf16x8*)(xw + (size_t)t * 8));
}

// ---------------- GEMM1: qkv = xw @ qkv_w^T + b ----------------------------
// 128x128 tile, 9216 blocks (1024 bm x 9 bn), bm-grouped XCD swizzle.
// bn 0..5 -> qkbuf row-major [M][768] (Q pre-scaled); bn 6..8 -> vT
// [win][head][dim][token] via Cst transpose. LDS: As/Bs overlaid by Cst.
__global__ __launch_bounds__(256) void gemm_qkv(
    const short* __restrict__ xw, const short* __restrict__ wt,
    const float* __restrict__ qkv_b, short* __restrict__ qkbuf,
    short* __restrict__ vT)
{
    __shared__ alignas(16) short smem[128 * 136];   // Cst; As/Bs overlay
    short* As = smem;                                // 4096 shorts
    short* Bs = smem + 4096;
    int tid = threadIdx.x;
    int hw = blockIdx.x;                             // 9216 = 8*1152
    int lb = (hw & 7) * 1152 + (hw >> 3);
    int bm = lb / 9, bn = lb - bm * 9;
    int m0 = bm * 128, n0 = bn * 128;

    int lane = tid & 63, wv = tid >> 6;
    int c0 = wv * 128 + lane, c1 = c0 + 64;
    int l0 = invswz(c0), l1 = invswz(c1);
    const short* Ag0 = xw + (size_t)(m0 + (l0 >> 2)) * CDIM + (l0 & 3) * 8;
    const short* Ag1 = xw + (size_t)(m0 + (l1 >> 2)) * CDIM + (l1 & 3) * 8;
    const short* Bg0 = wt + (size_t)(n0 + (l0 >> 2)) * CDIM + (l0 & 3) * 8;
    const short* Bg1 = wt + (size_t)(n0 + (l1 >> 2)) * CDIM + (l1 & 3) * 8;
    const short* Adst0 = (const short*)((const char*)As + wv * 2048);
    const short* Adst1 = (const short*)((const char*)As + wv * 2048 + 1024);
    const short* Bdst0 = (const short*)((const char*)Bs + wv * 2048);
    const short* Bdst1 = (const short*)((const char*)Bs + wv * 2048 + 1024);

    int wr = wv >> 1, wc = wv & 1;
    int lrow = lane & 15, lhi = lane >> 4;
    int arow = wr * 64 + lrow, brow = wc * 64 + lrow;
    const short* ard = As + ((((arow * 64 + lhi * 16)) ^ ((lrow & 7) << 4)) >> 1);
    const short* brd = Bs + ((((brow * 64 + lhi * 16)) ^ ((lrow & 7) << 4)) >> 1);

    f32x4 zero = {0.f, 0.f, 0.f, 0.f};
    f32x4 acc[4][4];
    #pragma unroll
    for (int i = 0; i < 4; i++)
        #pragma unroll
        for (int j = 0; j < 4; j++) acc[i][j] = zero;

    for (int k0 = 0; k0 < CDIM; k0 += 32) {
        gl16(Ag0 + k0, Adst0);
        gl16(Bg0 + k0, Bdst0);
        gl16(Ag1 + k0, Adst1);
        gl16(Bg1 + k0, Bdst1);
        __syncthreads();
        bf16x8 af[4], bfr[4];
        #pragma unroll
        for (int t = 0; t < 4; t++) af[t]  = *(const bf16x8*)(ard + t * 512);
        #pragma unroll
        for (int t = 0; t < 4; t++) bfr[t] = *(const bf16x8*)(brd + t * 512);
        #pragma unroll
        for (int i = 0; i < 4; i++)
            #pragma unroll
            for (int j = 0; j < 4; j++)
                acc[i][j] = __builtin_amdgcn_mfma_f32_16x16x32_bf16(af[i], bfr[j], acc[i][j], 0, 0, 0);
        __syncthreads();
    }
    // ---- epilogue: +bias (+q scale), Cst, then layout-specific stores ----
    #pragma unroll
    for (int tj = 0; tj < 4; tj++) {
        int col = wc * 64 + tj * 16 + lrow;
        int cg = n0 + col;
        float bias = qkv_b[cg];
        float sc = (cg < CDIM) ? SCALE_Q : 1.0f;
        #pragma unroll
        for (int ti = 0; ti < 4; ti++) {
            int row0 = wr * 64 + ti * 16 + lhi * 4;
            #pragma unroll
            for (int r = 0; r < 4; r++)
                smem[(row0 + r) * 136 + col] = f2bf((acc[ti][tj][r] + bias) * sc);
        }
    }
    __syncthreads();
    if (bn < 6) {
        // Q/K: row-major b128 NT stores, row stride 768
        #pragma unroll
        for (int i = 0; i < 8; i++) {
            int rr = i * 16 + (tid >> 4);
            int cc = (tid & 15) * 8;
            bf16x8 v = *(const bf16x8*)(smem + rr * 136 + cc);
            __builtin_nontemporal_store(v,
                (bf16x8*)(qkbuf + (size_t)(m0 + rr) * 768 + n0 + cc));
        }
    } else {
        // V: transpose to vT[win][head][dim][token]
        #pragma unroll
        for (int it = 0; it < 8; it++) {
            int t = it * 256 + tid;            // 2048 tasks
            int col = t >> 4, tk8 = t & 15;    // col 0..127, 8-token chunk
            bf16x8 v;
            #pragma unroll
            for (int j = 0; j < 8; j++)
                v[j] = smem[(tk8 * 8 + j) * 136 + col];
            int win = bm * 2 + (tk8 >> 3);
            int head = (bn - 6) * 4 + (col >> 5);
            int dim = col & 31;
            __builtin_nontemporal_store(v,
                (bf16x8*)(vT + (((size_t)win * HEADS + head) * 32 + dim) * 64 + (tk8 & 7) * 8));
        }
    }
}

// ---------------- attn: zero-LDS, zero-barrier; wave = (window, 3 heads) ---
__global__ __launch_bounds__(256) void attn_reg(
    const short* __restrict__ qkbuf, const short* __restrict__ vT,
    const float* __restrict__ biasP, short* __restrict__ attno)
{
    int tid = threadIdx.x;
    int lane = tid & 63, wv = tid >> 6;
    int lrow = lane & 15, lhi = lane >> 4;
    int w = blockIdx.x;
    int wIdx = w & 63;
    bool needmask = ((wIdx >> 3) == 7) || ((wIdx & 7) == 7);

    int rq[4], rk[4][4];
    #pragma unroll
    for (int qt = 0; qt < 4; qt++) rq[qt] = region_id(wIdx, qt * 16 + lrow);
    #pragma unroll
    for (int kt = 0; kt < 4; kt++)
        #pragma unroll
        for (int r = 0; r < 4; r++)
            rk[kt][r] = region_id(wIdx, kt * 16 + lhi * 4 + r);

    f32x4 zero = {0.f, 0.f, 0.f, 0.f};
    const short* qbase = qkbuf + (size_t)(w * 64) * 768;

    for (int hi = 0; hi < 3; hi++) {
        int h = wv * 3 + hi;
        // K fragments: A-op, lane holds K[key=kt*16+lrow][d=lhi*8+e]
        bf16x8 kf[4];
        #pragma unroll
        for (int kt = 0; kt < 4; kt++)
            kf[kt] = __builtin_nontemporal_load(
                (const bf16x8*)(qbase + (size_t)(kt * 16 + lrow) * 768 + CDIM + h * 32 + lhi * 8));
        // per-qt: S^T column block -> softmax -> P fragments
        bf16x8 pa[4][2];
        #pragma unroll
        for (int qt = 0; qt < 4; qt++) {
            bf16x8 qf = __builtin_nontemporal_load(
                (const bf16x8*)(qbase + (size_t)(qt * 16 + lrow) * 768 + h * 32 + lhi * 8));
            f32x4 st[4];
            __builtin_amdgcn_s_setprio(1);
            #pragma unroll
            for (int kt = 0; kt < 4; kt++)
                st[kt] = __builtin_amdgcn_mfma_f32_16x16x32_bf16(kf[kt], qf, zero, 0, 0, 0);
            __builtin_amdgcn_s_setprio(0);
            float pv[16]; float sum = 0.f;
            #pragma unroll
            for (int kt = 0; kt < 4; kt++) {
                f32x4 bb = *(const f32x4*)(biasP + (((size_t)h * 16 + kt * 4 + qt) * 64 + lane) * 4);
                #pragma unroll
                for (int r = 0; r < 4; r++) {
                    float p = __expf(st[kt][r] + bb[r]);
                    p = (needmask && (rq[qt] != rk[kt][r])) ? 0.f : p;
                    pv[kt * 4 + r] = p; sum += p;
                }
            }
            sum += __shfl_xor(sum, 16);
            sum += __shfl_xor(sum, 32);
            float rcp = 1.0f / sum;
            unsigned a0 = cvtpk(pv[0] * rcp, pv[1] * rcp);
            unsigned a1 = cvtpk(pv[2] * rcp, pv[3] * rcp);
            unsigned a2 = cvtpk(pv[4] * rcp, pv[5] * rcp);
            unsigned a3 = cvtpk(pv[6] * rcp, pv[7] * rcp);
            pa[qt][0] = regroup(a0, a1, a2, a3, lane);
            a0 = cvtpk(pv[8] * rcp,  pv[9] * rcp);
            a1 = cvtpk(pv[10] * rcp, pv[11] * rcp);
            a2 = cvtpk(pv[12] * rcp, pv[13] * rcp);
            a3 = cvtpk(pv[14] * rcp, pv[15] * rcp);
            pa[qt][1] = regroup(a0, a1, a2, a3, lane);
        }
        // V fragments from vT: A-op, lane holds V^T[dim=dt*16+lrow][key=ks2*32+lhi*8+e]
        const short* vb = vT + ((size_t)w * HEADS + h) * 32 * 64;
        bf16x8 vfrag[2][2];
        #pragma unroll
        for (int ks2 = 0; ks2 < 2; ks2++)
            #pragma unroll
            for (int dt = 0; dt < 2; dt++)
                vfrag[ks2][dt] = __builtin_nontemporal_load(
                    (const bf16x8*)(vb + (size_t)(dt * 16 + lrow) * 64 + ks2 * 32 + lhi * 8));
        // PV^T: ao2[qt][dt], col=query(lane&15), rows=4 consecutive dims
        f32x4 ao2[4][2];
        #pragma unroll
        for (int qt = 0; qt < 4; qt++) { ao2[qt][0] = zero; ao2[qt][1] = zero; }
        __builtin_amdgcn_s_setprio(1);
        #pragma unroll
        for (int ks2 = 0; ks2 < 2; ks2++)
            #pragma unroll
            for (int qt = 0; qt < 4; qt++) {
                ao2[qt][0] = __builtin_amdgcn_mfma_f32_16x16x32_bf16(vfrag[ks2][0], pa[qt][ks2], ao2[qt][0], 0, 0, 0);
                ao2[qt][1] = __builtin_amdgcn_mfma_f32_16x16x32_bf16(vfrag[ks2][1], pa[qt][ks2], ao2[qt][1], 0, 0, 0);
            }
        __builtin_amdgcn_s_setprio(0);
        // paired 8B NT stores (full 64B (token,head) line per 16-lane group)
        short* abase = attno + (size_t)(w * 64) * CDIM + h * 32 + lhi * 4;
        #pragma unroll
        for (int qt = 0; qt < 4; qt++) {
            int token = qt * 16 + lrow;
            short* p0 = abase + (size_t)token * CDIM;
            u32x2 s0, s1;
            s0[0] = cvtpk(ao2[qt][0][0], ao2[qt][0][1]);
            s0[1] = cvtpk(ao2[qt][0][2], ao2[qt][0][3]);
            s1[0] = cvtpk(ao2[qt][1][0], ao2[qt][1][1]);
            s1[1] = cvtpk(ao2[qt][1][2], ao2[qt][1][3]);
            __builtin_nontemporal_store(s0, (u32x2*)(p0));
            __builtin_nontemporal_store(s1, (u32x2*)(p0 + 16));
        }
    }
}

// ---------------- GEMM2: out = attno @ proj_w^T + b, window-reverse --------
__global__ __launch_bounds__(256) void gemm_proj(
    const short* __restrict__ a, const short* __restrict__ wt,
    const float* __restrict__ proj_b, float* __restrict__ out)
{
    __shared__ alignas(16) short As[4096];
    __shared__ alignas(16) short Bs[4096];
    int tid = threadIdx.x;
    int hw = blockIdx.x;                       // 3072 blocks, %8==0
    int lb = (hw & 7) * 384 + (hw >> 3);
    int bm = lb / 3, bn = lb - bm * 3;
    int m0 = bm * 128, n0 = bn * 128;

    int lane = tid & 63, wv = tid >> 6;
    int c0 = wv * 128 + lane, c1 = c0 + 64;
    int l0 = invswz(c0), l1 = invswz(c1);
    const short* Ag0 = a + (size_t)(m0 + (l0 >> 2)) * CDIM + (l0 & 3) * 8;
    const short* Ag1 = a + (size_t)(m0 + (l1 >> 2)) * CDIM + (l1 & 3) * 8;
    const short* Bg0 = wt + (size_t)(n0 + (l0 >> 2)) * CDIM + (l0 & 3) * 8;
    const short* Bg1 = wt + (size_t)(n0 + (l1 >> 2)) * CDIM + (l1 & 3) * 8;
    const short* Adst0 = (const short*)((const char*)As + wv * 2048);
    const short* Adst1 = (const short*)((const char*)As + wv * 2048 + 1024);
    const short* Bdst0 = (const short*)((const char*)Bs + wv * 2048);
    const short* Bdst1 = (const short*)((const char*)Bs + wv * 2048 + 1024);

    int wr = wv >> 1, wc = wv & 1;
    int lrow = lane & 15, lhi = lane >> 4;
    int arow = wr * 64 + lrow, brow = wc * 64 + lrow;
    const short* ard = As + ((((arow * 64 + lhi * 16)) ^ ((lrow & 7) << 4)) >> 1);
    const short* brd = Bs + ((((brow * 64 + lhi * 16)) ^ ((lrow & 7) << 4)) >> 1);

    f32x4 zero = {0.f, 0.f, 0.f, 0.f};
    f32x4 acc[4][4];
    #pragma unroll
    for (int i = 0; i < 4; i++)
        #pragma unroll
        for (int j = 0; j < 4; j++) acc[i][j] = zero;

    for (int k0 = 0; k0 < CDIM; k0 += 32) {
        gl16(Ag0 + k0, Adst0);
        gl16(Bg0 + k0, Bdst0);
        gl16(Ag1 + k0, Adst1);
        gl16(Bg1 + k0, Bdst1);
        __syncthreads();
        bf16x8 af[4], bfr[4];
        #pragma unroll
        for (int t = 0; t < 4; t++) af[t]  = *(const bf16x8*)(ard + t * 512);
        #pragma unroll
        for (int t = 0; t < 4; t++) bfr[t] = *(const bf16x8*)(brd + t * 512);
        #pragma unroll
        for (int i = 0; i < 4; i++)
            #pragma unroll
            for (int j = 0; j < 4; j++)
                acc[i][j] = __builtin_amdgcn_mfma_f32_16x16x32_bf16(af[i], bfr[j], acc[i][j], 0, 0, 0);
        __syncthreads();
    }
    // epilogue: window reverse + unshift, fp32 NT out
    #pragma unroll
    for (int ti = 0; ti < 4; ti++) {
        #pragma unroll
        for (int r = 0; r < 4; r++) {
            int m = m0 + wr * 64 + ti * 16 + lhi * 4 + r;
            int b = m >> 12, wIdx = (m >> 6) & 63, tok = m & 63;
            int gh = ((wIdx >> 3) << 3) + (tok >> 3);
            int gw = (wIdx & 7) * 8 + (tok & 7);
            int ih = (gh + SHIFT_) & 63, iw = (gw + SHIFT_) & 63;
            size_t ob = ((size_t)(b << 12) + ih * 64 + iw) * CDIM;
            #pragma unroll
            for (int tj = 0; tj < 4; tj++) {
                int col = n0 + wc * 64 + tj * 16 + lrow;
                float v = acc[ti][tj][r] + proj_b[col];
                __builtin_nontemporal_store(v, &out[ob + col]);
            }
        }
    }
}

extern "C" void kernel_launch(void* const* d_in, const int* in_sizes, int n_in,
                              void* d_out, int out_size, void* d_ws, size_t ws_size,
                              hipStream_t stream) {
    const float* x          = (const float*)d_in[0];
    const float* qkv_w      = (const float*)d_in[1];
    const float* qkv_b      = (const float*)d_in[2];
    const float* proj_w     = (const float*)d_in[3];
    const float* proj_b     = (const float*)d_in[4];
    const float* bias_table = (const float*)d_in[5];
    const int*   rel_index  = (const int*)d_in[6];
    float* out = (float*)d_out;
    char* ws = (char*)d_ws;

    short* qkvwt = (short*)(ws);                    //    884736 B
    short* projwt = (short*)(ws + 884736);          //    294912 B
    float* biasP  = (float*)(ws + 1179648);         //    196608 B
    short* xw     = (short*)(ws + 1376256);         // 100663296 B
    short* qkbuf  = (short*)(ws + 102039552);       // 201326592 B
    short* vT     = (short*)(ws + 303366144);       // 100663296 B
    short* attno  = (short*)(ws + 404029440);       // 100663296 B -> ~505 MB

    prep_kernel<<<1728, 256, 0, stream>>>(qkv_w, proj_w, bias_table, rel_index,
                                          qkvwt, projwt, biasP);
    xwin_kernel<<<24576, 256, 0, stream>>>(x, xw);
    gemm_qkv<<<9216, 256, 0, stream>>>(xw, qkvwt, qkv_b, qkbuf, vT);
    attn_reg<<<2048, 256, 0, stream>>>(qkbuf, vT, biasP, attno);
    gemm_proj<<<3072, 256, 0, stream>>>(attno, projwt, proj_b, out);
}